// Round 1
// baseline (156.327 us; speedup 1.0000x reference)
//
#include <hip/hip_runtime.h>
#include <stdint.h>

// out[n,o] = sum_{d,i} q[n,d] x[n,i] W1[d,i,o] + sum_d q[n,d] b1[d,o]
//          = (A @ Wf)[n,o] + (q @ b1)[n,o],  A[n, d*256+i] = q[n,d]*x[n,i]
// GEMM M=4096 N=256 K=16384, fp16 MFMA 32x32x16, fp32 accum.
// A is never materialized: within a BK=32 chunk d is fixed, so the A-frag is
// an x-frag (LDS-resident) times a per-lane q scalar (v_pk_mul_f16).

typedef _Float16 f16;
typedef f16 f16x8 __attribute__((ext_vector_type(8)));
typedef float f32x16 __attribute__((ext_vector_type(16)));

#define NROWS 4096
#define DIN 256
#define DOUT 256
#define QDIM 64
#define NCHUNK 512   // K=16384 / BK=32
#define SPLIT 8      // split-K groups (8 d's each)
#define CHB 64       // chunks per block
#define MBLK 64      // rows per block

// async global->LDS 16B copy; lds dest is wave-uniform base + lane*16.
// Casts go through uintptr_t (LDS aperture is 4GB-aligned, low 32 bits = LDS offset).
__device__ __forceinline__ void gl_lds16(const void* g, void* s) {
  __builtin_amdgcn_global_load_lds(
      (const __attribute__((address_space(1))) void*)(uintptr_t)g,
      (__attribute__((address_space(3))) void*)(uint32_t)(uintptr_t)s,
      16, 0, 0);
}

// ---- Pre-kernel: W1 fp32 [k=d*256+i][o] -> fragment-major fp16 ----
// chunk g (k0=g*32): element ((s*2+h)*256 + n)*8 + j  <-  W1[(k0+s*16+h*8+j)*256 + n]
__global__ __launch_bounds__(256) void conv_w(const float* __restrict__ W,
                                              f16* __restrict__ Wt) {
  const int g = blockIdx.x;  // 0..511
  const int t = threadIdx.x;
  const int k0 = g << 5;
#pragma unroll
  for (int r = 0; r < 4; ++r) {
    const int gidx = (r << 8) + t;   // (s*2+h)*256 + n
    const int n = gidx & 255;
    const int sh = gidx >> 8;        // s*2+h
    f16x8 h;
#pragma unroll
    for (int j = 0; j < 8; ++j) {
      h[j] = (f16)W[(size_t)(k0 + (sh << 3) + j) * 256 + n];  // coalesced over n
    }
    *(f16x8*)(Wt + (size_t)g * 8192 + (size_t)gidx * 8) = h;
  }
}

// ---- Pre-kernel: x fp32 -> fragment-major fp16 per 64-row block ----
// element (((ic*2+s)*2+h)*64 + row)*8 + j  <-  x[mb*64+row][ic*32+s*16+h*8+j]
__global__ __launch_bounds__(256) void conv_x(const float* __restrict__ X,
                                              f16* __restrict__ Xt) {
  const int mb = blockIdx.x;  // 0..63
  const int t = threadIdx.x;
#pragma unroll
  for (int r = 0; r < 8; ++r) {
    const int gidx = (r << 8) + t;  // hsic*64 + row ; i0 = hsic*8
    const int row = gidx & 63;
    const int hsic = gidx >> 6;
    const float* src = X + (size_t)(mb * 64 + row) * 256 + hsic * 8;
    float4 a = *(const float4*)src;
    float4 b = *(const float4*)(src + 4);
    f16x8 h;
    h[0] = (f16)a.x; h[1] = (f16)a.y; h[2] = (f16)a.z; h[3] = (f16)a.w;
    h[4] = (f16)b.x; h[5] = (f16)b.y; h[6] = (f16)b.z; h[7] = (f16)b.w;
    *(f16x8*)(Xt + (size_t)mb * 16384 + (size_t)gidx * 8) = h;
  }
}

// ---- bias init: out[n,o] = sum_d q[n,d] b1[d,o]  (also clears 0xAA poison) ----
__global__ __launch_bounds__(256) void bias_init(const float* __restrict__ Q,
                                                 const float* __restrict__ B1,
                                                 float* __restrict__ out) {
  __shared__ float qs[QDIM];
  const int n = blockIdx.x;
  const int t = threadIdx.x;
  if (t < QDIM) qs[t] = Q[(size_t)n * QDIM + t];
  __syncthreads();
  float acc = 0.f;
#pragma unroll 8
  for (int d = 0; d < QDIM; ++d) acc += qs[d] * B1[d * 256 + t];
  out[(size_t)n * 256 + t] = acc;
}

// ---- main GEMM: 512 blocks = 64 row-blocks x 8 split-K groups ----
__global__ __launch_bounds__(256, 2) void mlp_main(const float* __restrict__ Q,
                                                   const f16* __restrict__ Wt,
                                                   const f16* __restrict__ Xt,
                                                   float* __restrict__ out) {
  __shared__ f16 s_x[16384];     // 32 KB: x tile, resident whole K-loop
  __shared__ f16 s_w[2][8192];   // 2x16 KB: W chunk double buffer

  const int bid = blockIdx.x;
  const int mb = bid & 63;       // row block (adjacent blocks share W segment -> L2)
  const int sg = bid >> 6;       // split-K group: d in [sg*8, sg*8+8)
  const int t = threadIdx.x;
  const int w = t >> 6;          // wave 0..3 -> cols [w*64, w*64+64)
  const int l = t & 63;
  const int l31 = l & 31;
  const int hf = l >> 5;

  // stage x tile (32 KB) + first W chunk (16 KB), async
  const char* xg = (const char*)(Xt + (size_t)mb * 16384);
  char* xs = (char*)s_x;
#pragma unroll
  for (int i = 0; i < 8; ++i) {
    const int off = ((w * 8 + i) << 10) + (l << 4);
    gl_lds16(xg + off, xs + off);
  }
  const char* wg = (const char*)(Wt + (size_t)sg * (CHB * 8192));
#pragma unroll
  for (int i = 0; i < 4; ++i) {
    const int off = ((w * 4 + i) << 10) + (l << 4);
    gl_lds16(wg + off, (char*)s_w[0] + off);
  }

  // per-lane q scalars: q[mb*64 + mt*32 + l31][sg*8 + dd]
  f16 qr[2][8];
#pragma unroll
  for (int mt = 0; mt < 2; ++mt) {
    const float* qp = Q + (size_t)(mb * 64 + mt * 32 + l31) * QDIM + sg * 8;
#pragma unroll
    for (int dd = 0; dd < 8; ++dd) qr[mt][dd] = (f16)qp[dd];
  }

  f32x16 acc[2][2];
#pragma unroll
  for (int a = 0; a < 2; ++a)
#pragma unroll
    for (int b = 0; b < 2; ++b)
#pragma unroll
      for (int r = 0; r < 16; ++r) acc[a][b][r] = 0.f;

  __syncthreads();  // barrier drains vmcnt(0): staged data visible

  // fixed per-lane LDS element offsets (conflict-free: 16 lanes -> 256B contiguous)
  const int xb0 = (hf * 64 + l31) * 8;            // mt=0 ; mt=1 at +256
  const int wb0 = (hf * 256 + w * 64 + l31) * 8;  // nt=0 ; nt=1 at +256

  for (int gl = 0; gl < CHB; ++gl) {
    const int p = gl & 1;
    if (gl + 1 < CHB) {  // prefetch next W chunk into other buffer
      const char* src = wg + (size_t)(gl + 1) * 16384;
      char* dst = (char*)s_w[p ^ 1];
#pragma unroll
      for (int i = 0; i < 4; ++i) {
        const int off = ((w * 4 + i) << 10) + (l << 4);
        gl_lds16(src + off, dst + off);
      }
    }
    const int dd = gl >> 3;          // local d index
    const int icb = (gl & 7) << 11;  // ic*2048 elements
    const f16 qa0 = qr[0][dd];
    const f16 qa1 = qr[1][dd];
#pragma unroll
    for (int s = 0; s < 2; ++s) {    // two k=16 MFMA steps per BK=32 chunk
      const int xo = icb + (s << 10);
      const int wo = s << 12;
      f16x8 xf0 = *(const f16x8*)(s_x + xo + xb0);
      f16x8 xf1 = *(const f16x8*)(s_x + xo + xb0 + 256);
      f16x8 bf0 = *(const f16x8*)(&s_w[p][0] + wo + wb0);
      f16x8 bf1 = *(const f16x8*)(&s_w[p][0] + wo + wb0 + 256);
      f16x8 a0 = xf0 * qa0;  // A-frag = x-frag * q[row,d] : 4x v_pk_mul_f16
      f16x8 a1 = xf1 * qa1;
      acc[0][0] = __builtin_amdgcn_mfma_f32_32x32x16_f16(a0, bf0, acc[0][0], 0, 0, 0);
      acc[1][0] = __builtin_amdgcn_mfma_f32_32x32x16_f16(a1, bf0, acc[1][0], 0, 0, 0);
      acc[0][1] = __builtin_amdgcn_mfma_f32_32x32x16_f16(a0, bf1, acc[0][1], 0, 0, 0);
      acc[1][1] = __builtin_amdgcn_mfma_f32_32x32x16_f16(a1, bf1, acc[1][1], 0, 0, 0);
    }
    __syncthreads();  // protects double buffer; also drains prefetch for next iter
  }

  // epilogue: atomic accumulate split-K partials onto bias-initialized out.
  // C/D layout (32x32): col = lane&31, row = (reg&3) + 8*(reg>>2) + 4*(lane>>5)
#pragma unroll
  for (int mt = 0; mt < 2; ++mt) {
#pragma unroll
    for (int nt = 0; nt < 2; ++nt) {
#pragma unroll
      for (int r = 0; r < 16; ++r) {
        const int row = mb * 64 + mt * 32 + (r & 3) + ((r >> 2) << 3) + (hf << 2);
        const int col = w * 64 + nt * 32 + l31;
        atomicAdd(out + (size_t)row * DOUT + col, acc[mt][nt][r]);
      }
    }
  }
}

extern "C" void kernel_launch(void* const* d_in, const int* in_sizes, int n_in,
                              void* d_out, int out_size, void* d_ws, size_t ws_size,
                              hipStream_t stream) {
  (void)in_sizes; (void)n_in; (void)out_size; (void)ws_size;
  const float* x  = (const float*)d_in[0];   // [4096,256]
  const float* q  = (const float*)d_in[1];   // [4096,64]
  const float* W1 = (const float*)d_in[2];   // [64,256,256]
  const float* b1 = (const float*)d_in[3];   // [64,256]
  float* out = (float*)d_out;                // [4096,256] fp32

  // workspace: Wt fp16 8 MB @0, Xt fp16 2 MB @8MB  (needs ws_size >= 10.5 MB)
  f16* Wt = (f16*)d_ws;
  f16* Xt = (f16*)((char*)d_ws + (size_t)NCHUNK * 8192 * 2);

  conv_w<<<NCHUNK, 256, 0, stream>>>(W1, Wt);
  conv_x<<<NROWS / MBLK, 256, 0, stream>>>(x, Xt);
  bias_init<<<NROWS, 256, 0, stream>>>(q, b1, out);
  mlp_main<<<(NROWS / MBLK) * SPLIT, 256, 0, stream>>>(q, Wt, Xt, out);
}